// Round 12
// baseline (149.152 us; speedup 1.0000x reference)
//
#include <hip/hip_runtime.h>
#include <hip/hip_bf16.h>
#include <cstddef>

typedef __attribute__((ext_vector_type(8))) short short8;
typedef __attribute__((ext_vector_type(4))) float f32x4;

__device__ inline unsigned short f2bf(float f) {
  unsigned int u = __float_as_uint(f);
  u += 0x7fffu + ((u >> 16) & 1u);
  return (unsigned short)(u >> 16);
}
__device__ inline unsigned int pkbf(float a, float b) {
  __hip_bfloat162 h = __float22bfloat162_rn(make_float2(a, b));
  union { __hip_bfloat162 h2; unsigned int u; } cv;
  cv.h2 = h;
  return cv.u;
}

// Fused prep: z=0/1/2 -> transpose+cast Wq/Wkv/Wo (f32 [R,C] -> bf16 [C,R]);
// z=3 -> pack key mask into 64-bit words. All branch conditions block-uniform.
__global__ __launch_bounds__(256) void prep_kernel(
    const float* __restrict__ Wq, const float* __restrict__ Wkv,
    const float* __restrict__ Wo, const int* __restrict__ mask,
    unsigned short* __restrict__ Wq_t, unsigned short* __restrict__ Wkv_t,
    unsigned short* __restrict__ Wo_t, unsigned long long* __restrict__ mpk) {
  const int z = blockIdx.z;
  if (z == 3) {
    if (blockIdx.y != 0) return;
    int wid = blockIdx.x * 4 + (threadIdx.x >> 6);  // 0..63
    int lane = threadIdx.x & 63;
    unsigned long long b0 = __ballot(mask[wid * 64 + lane] != 0);
    if (lane == 0) mpk[wid] = b0;
    unsigned long long b1 = __ballot(mask[(wid + 64) * 64 + lane] != 0);
    if (lane == 0) mpk[wid + 64] = b1;
    return;
  }
  const float* src = (z == 0) ? Wq : (z == 1) ? Wkv : Wo;
  unsigned short* dst = (z == 0) ? Wq_t : (z == 1) ? Wkv_t : Wo_t;
  const int R = 512, C = (z == 1) ? 1024 : 512;
  if (blockIdx.x * 64 >= C) return;  // block-uniform
  __shared__ float tile[64][65];
  int c0 = blockIdx.x * 64, r0 = blockIdx.y * 64;
  int tx = threadIdx.x & 63, ty = threadIdx.x >> 6;
  for (int i = ty; i < 64; i += 4)
    tile[i][tx] = src[(size_t)(r0 + i) * C + c0 + tx];
  __syncthreads();
  for (int i = ty; i < 64; i += 4)
    dst[(size_t)(c0 + i) * R + r0 + tx] = f2bf(tile[tx][i]);
}

// C = A[M,K] * Bt[N,K]^T. Round-7 structure (measured fastest):
// direct global->LDS staging, two __syncthreads per K-step, no lambdas,
// no inline asm, no reg-prefetch. Tile (MT*32) x 128, 4 waves 2x2.
// MODE 0: C0 bf16 [M,N] scaled by oscale
// MODE 1: split kv: col<512 -> C0 bf16 [M,512]; col>=512 -> C1 vt[b,h,d,m]
// MODE 2: C0 f32 [M,N] + bias
template <int MT, int MODE, bool AF32>
__global__ __launch_bounds__(256) void gemm_kernel(
    const void* __restrict__ Ap, const unsigned short* __restrict__ Bt,
    void* __restrict__ C0, unsigned short* __restrict__ C1,
    const float* __restrict__ bias, int M, int N, int K, float oscale) {
  __shared__ unsigned short As[MT * 32][72];
  __shared__ unsigned short Bs[128][72];
  const int bm = blockIdx.y * (MT * 32), bn = blockIdx.x * 128;
  const int tid = threadIdx.x;
  const int wave = tid >> 6, lane = tid & 63;
  const int wr = (wave >> 1) * (MT * 16), wc = (wave & 1) * 64;
  const int l15 = lane & 15, lq = lane >> 4;
  const int sr = tid >> 3, sc = (tid & 7) * 8;
  f32x4 acc[MT][4] = {};

  const float* Af = (const float*)Ap;
  const unsigned short* Ab = (const unsigned short*)Ap;

  for (int k0 = 0; k0 < K; k0 += 64) {
    __syncthreads();
#pragma unroll
    for (int p = 0; p < MT; ++p) {
      int r = sr + p * 32;
      if constexpr (AF32) {
        const float4 f0 = *(const float4*)(Af + (size_t)(bm + r) * K + k0 + sc);
        const float4 f1 = *(const float4*)(Af + (size_t)(bm + r) * K + k0 + sc + 4);
        uint4 u;
        u.x = pkbf(f0.x, f0.y);
        u.y = pkbf(f0.z, f0.w);
        u.z = pkbf(f1.x, f1.y);
        u.w = pkbf(f1.z, f1.w);
        *(uint4*)(&As[r][sc]) = u;
      } else {
        *(uint4*)(&As[r][sc]) = *(const uint4*)(Ab + (size_t)(bm + r) * K + k0 + sc);
      }
    }
#pragma unroll
    for (int p = 0; p < 4; ++p)
      *(uint4*)(&Bs[sr + p * 32][sc]) = *(const uint4*)(Bt + (size_t)(bn + sr + p * 32) * K + k0 + sc);
    __syncthreads();
#pragma unroll
    for (int kk = 0; kk < 2; ++kk) {
      short8 af[MT], bfr[4];
#pragma unroll
      for (int mt = 0; mt < MT; ++mt)
        af[mt] = *(const short8*)(&As[wr + mt * 16 + l15][kk * 32 + lq * 8]);
#pragma unroll
      for (int nt = 0; nt < 4; ++nt)
        bfr[nt] = *(const short8*)(&Bs[wc + nt * 16 + l15][kk * 32 + lq * 8]);
#pragma unroll
      for (int mt = 0; mt < MT; ++mt)
#pragma unroll
        for (int nt = 0; nt < 4; ++nt)
          acc[mt][nt] = __builtin_amdgcn_mfma_f32_16x16x32_bf16(af[mt], bfr[nt], acc[mt][nt], 0, 0, 0);
    }
  }

#pragma unroll
  for (int mt = 0; mt < MT; ++mt)
#pragma unroll
    for (int nt = 0; nt < 4; ++nt) {
      int row0 = bm + wr + mt * 16 + lq * 4;
      int col = bn + wc + nt * 16 + l15;
      if constexpr (MODE == 1) {
        if (col >= 512) {  // V^T path: 4 consecutive m -> one 8B store
          int bb = row0 >> 11, m = row0 & 2047;
          int hd = col - 512;  // h*64+d
          uint2 w;
          w.x = pkbf(acc[mt][nt][0], acc[mt][nt][1]);
          w.y = pkbf(acc[mt][nt][2], acc[mt][nt][3]);
          *(uint2*)(C1 + ((size_t)bb * 512 + hd) * 2048 + m) = w;
          continue;
        }
      }
#pragma unroll
      for (int j = 0; j < 4; ++j) {
        int row = row0 + j;
        float v = acc[mt][nt][j];
        if constexpr (MODE == 0) {
          ((unsigned short*)C0)[(size_t)row * N + col] = f2bf(v * oscale);
        } else if constexpr (MODE == 1) {
          ((unsigned short*)C0)[(size_t)row * 512 + col] = f2bf(v);
        } else {
          ((float*)C0)[(size_t)row * N + col] = v + bias[col];
        }
      }
    }
}

// Flash attention, swapped-MFMA in-register softmax, permuted-K layout.
// rt=2: 32 q-rows per wave -> each kf/vf ds_read_b128 feeds TWO MFMAs
// (LDS-BW bound per r11 counters; this halves LDS reads per q-row).
// 4 waves x 32 q-rows = 128 q-rows/block; 256 thr; grid (32,16) = 2 blk/CU.
// LDS stride 72 (empirical best). T13 defer-max THR=8 (exp2 domain).
// Double-buffered LDS, ONE __syncthreads per KV-tile, no asm/lambdas.
__global__ __launch_bounds__(256) void attn_kernel(
    const unsigned short* __restrict__ Q, const unsigned short* __restrict__ Kb,
    const unsigned short* __restrict__ Vt, const unsigned long long* __restrict__ Mpk,
    unsigned short* __restrict__ O) {
  __shared__ unsigned short Ks[2][64][72];
  __shared__ unsigned short Vs[2][64][72];
  const int b = blockIdx.x >> 3, h = blockIdx.x & 7;
  const int tid = threadIdx.x, lane = tid & 63;
  const int wave = tid >> 6;
  const int l15 = lane & 15, lq = lane >> 4;
  const int wrow = blockIdx.y * 128 + wave * 32;

  // Q fragments: rt in {0,1} -> rows wrow+rt*16+l15; d-elems kk*32+lq*8..+7
  const unsigned short* Qr0 = Q + (size_t)(b * 2048 + wrow + l15) * 512 + h * 64;
  const unsigned short* Qr1 = Q + (size_t)(b * 2048 + wrow + 16 + l15) * 512 + h * 64;
  short8 q00 = *(const short8*)(Qr0 + lq * 8);
  short8 q01 = *(const short8*)(Qr0 + 32 + lq * 8);
  short8 q10 = *(const short8*)(Qr1 + lq * 8);
  short8 q11 = *(const short8*)(Qr1 + 32 + lq * 8);

  f32x4 o0[4] = {}, o1[4] = {};  // O^T[d = dt*16+lq*4+j][q = l15] per rt
  float mrun0 = -1e30f, lrun0 = 0.f;
  float mrun1 = -1e30f, lrun1 = 0.f;

  const unsigned short* Kg = Kb + (size_t)b * 2048 * 512 + h * 64;
  const unsigned short* Vg = Vt + (size_t)(b * 8 + h) * 64 * 2048;
  const unsigned long long* mp = Mpk + b * 32;

  const int str = tid >> 3;        // 0..31 (key g within tile; also g+32)
  const int stc = (tid & 7) * 8;   // elem col within 64
  // permuted K row: g -> (g&7>>1)*16 + ((g>>3)&3)*4 + (g>>5)*2 + (g&1);
  // perm(g+32) = perm(g) + 2 for g in 0..31
  const int kprow = ((str & 7) >> 1) * 16 + ((str >> 3) & 3) * 4 + (str & 1);
  const int msh = lq * 8;

  // prefetch tile 0 (named scalars only)
  uint4 kr0 = *(const uint4*)(Kg + (size_t)str * 512 + stc);
  uint4 kr1 = *(const uint4*)(Kg + (size_t)(str + 32) * 512 + stc);
  uint4 vr0 = *(const uint4*)(Vg + (size_t)str * 2048 + stc);
  uint4 vr1 = *(const uint4*)(Vg + (size_t)(str + 32) * 2048 + stc);
  unsigned long long mreg = mp[0];

  for (int mb = 0; mb < 2048; mb += 64) {
    const int buf = (mb >> 6) & 1;
    // implicit vmcnt wait on staged regs here (thread-local)
    *(uint4*)(&Ks[buf][kprow][stc]) = kr0;
    *(uint4*)(&Ks[buf][kprow + 2][stc]) = kr1;
    *(uint4*)(&Vs[buf][str][stc]) = vr0;
    *(uint4*)(&Vs[buf][str + 32][stc]) = vr1;
    unsigned long long mcur = mreg;
    __syncthreads();  // write->read sync for buf; prefetch below never crosses a barrier
    if (mb + 64 < 2048) {
      kr0 = *(const uint4*)(Kg + (size_t)(mb + 64 + str) * 512 + stc);
      kr1 = *(const uint4*)(Kg + (size_t)(mb + 64 + str + 32) * 512 + stc);
      vr0 = *(const uint4*)(Vg + (size_t)str * 2048 + mb + 64 + stc);
      vr1 = *(const uint4*)(Vg + (size_t)(str + 32) * 2048 + mb + 64 + stc);
      mreg = mp[(mb >> 6) + 1];
    }

    // swapped QK^T on permuted keys: s{rt}[ct][j] = S^T[key=kappa(ct,lq,j)][q]
    // kappa = (j>>1)*32 + lq*8 + 2ct + (j&1); kf shared across rt
    f32x4 s0[4] = {}, s1[4] = {};
#pragma unroll
    for (int ct = 0; ct < 4; ++ct) {
      short8 kf = *(const short8*)(&Ks[buf][ct * 16 + l15][lq * 8]);
      s0[ct] = __builtin_amdgcn_mfma_f32_16x16x32_bf16(kf, q00, s0[ct], 0, 0, 0);
      s1[ct] = __builtin_amdgcn_mfma_f32_16x16x32_bf16(kf, q10, s1[ct], 0, 0, 0);
    }
#pragma unroll
    for (int ct = 0; ct < 4; ++ct) {
      short8 kf = *(const short8*)(&Ks[buf][ct * 16 + l15][32 + lq * 8]);
      s0[ct] = __builtin_amdgcn_mfma_f32_16x16x32_bf16(kf, q01, s0[ct], 0, 0, 0);
      s1[ct] = __builtin_amdgcn_mfma_f32_16x16x32_bf16(kf, q11, s1[ct], 0, 0, 0);
    }

    // mask: key kappa(ct,lq,j); extraction shared across rt (same keys)
    unsigned int mlo = __builtin_amdgcn_readfirstlane((unsigned int)mcur);
    unsigned int mhi = __builtin_amdgcn_readfirstlane((unsigned int)(mcur >> 32));
#pragma unroll
    for (int ct = 0; ct < 4; ++ct) {
      unsigned int lo2 = (mlo >> (msh + 2 * ct)) & 3u;
      unsigned int hi2 = (mhi >> (msh + 2 * ct)) & 3u;
      s0[ct][0] = (lo2 & 1u) ? s0[ct][0] : -1e30f;
      s0[ct][1] = (lo2 & 2u) ? s0[ct][1] : -1e30f;
      s0[ct][2] = (hi2 & 1u) ? s0[ct][2] : -1e30f;
      s0[ct][3] = (hi2 & 2u) ? s0[ct][3] : -1e30f;
      s1[ct][0] = (lo2 & 1u) ? s1[ct][0] : -1e30f;
      s1[ct][1] = (lo2 & 2u) ? s1[ct][1] : -1e30f;
      s1[ct][2] = (hi2 & 1u) ? s1[ct][2] : -1e30f;
      s1[ct][3] = (hi2 & 2u) ? s1[ct][3] : -1e30f;
    }

    float t0 = -1e30f, t1 = -1e30f;
#pragma unroll
    for (int ct = 0; ct < 4; ++ct)
#pragma unroll
      for (int j = 0; j < 4; ++j) {
        t0 = fmaxf(t0, s0[ct][j]);
        t1 = fmaxf(t1, s1[ct][j]);
      }
    t0 = fmaxf(t0, __shfl_xor(t0, 16));
    t0 = fmaxf(t0, __shfl_xor(t0, 32));
    t1 = fmaxf(t1, __shfl_xor(t1, 16));
    t1 = fmaxf(t1, __shfl_xor(t1, 32));

    // T13 defer: single wave-uniform decision for both row-tiles
    const bool grow = !__all(t0 <= mrun0 + 8.0f && t1 <= mrun1 + 8.0f);
    float fac0 = 1.0f, fac1 = 1.0f;
    if (grow) {
      float mn0 = fmaxf(mrun0, t0), mn1 = fmaxf(mrun1, t1);
      fac0 = __builtin_amdgcn_exp2f(mrun0 - mn0);
      fac1 = __builtin_amdgcn_exp2f(mrun1 - mn1);
      mrun0 = mn0;
      mrun1 = mn1;
    }

    float rs0 = 0.f, rs1 = 0.f;
    unsigned int xp0[4][2], xp1[4][2];  // xp[ct][half]: keys kappa(ct,lq,2h(+1))
#pragma unroll
    for (int ct = 0; ct < 4; ++ct) {
      float a0 = __builtin_amdgcn_exp2f(s0[ct][0] - mrun0);
      float a1 = __builtin_amdgcn_exp2f(s0[ct][1] - mrun0);
      float a2 = __builtin_amdgcn_exp2f(s0[ct][2] - mrun0);
      float a3 = __builtin_amdgcn_exp2f(s0[ct][3] - mrun0);
      rs0 += (a0 + a1) + (a2 + a3);
      xp0[ct][0] = pkbf(a0, a1);
      xp0[ct][1] = pkbf(a2, a3);
      float c0 = __builtin_amdgcn_exp2f(s1[ct][0] - mrun1);
      float c1 = __builtin_amdgcn_exp2f(s1[ct][1] - mrun1);
      float c2 = __builtin_amdgcn_exp2f(s1[ct][2] - mrun1);
      float c3 = __builtin_amdgcn_exp2f(s1[ct][3] - mrun1);
      rs1 += (c0 + c1) + (c2 + c3);
      xp1[ct][0] = pkbf(c0, c1);
      xp1[ct][1] = pkbf(c2, c3);
    }
    rs0 += __shfl_xor(rs0, 16);
    rs0 += __shfl_xor(rs0, 32);
    rs1 += __shfl_xor(rs1, 16);
    rs1 += __shfl_xor(rs1, 32);

    if (grow) {
      lrun0 = lrun0 * fac0 + rs0;
      lrun1 = lrun1 * fac1 + rs1;
#pragma unroll
      for (int dt = 0; dt < 4; ++dt)
#pragma unroll
        for (int j = 0; j < 4; ++j) {
          o0[dt][j] *= fac0;
          o1[dt][j] *= fac1;
        }
    } else {
      lrun0 += rs0;
      lrun1 += rs1;
    }

    // PV swapped: O^T += V^T · P^T; B-frags lane-local; vf shared across rt
#pragma unroll
    for (int kk = 0; kk < 2; ++kk) {
      union { unsigned int u[4]; short8 s8; } pc0, pc1;
      pc0.u[0] = xp0[0][kk]; pc0.u[1] = xp0[1][kk];
      pc0.u[2] = xp0[2][kk]; pc0.u[3] = xp0[3][kk];
      pc1.u[0] = xp1[0][kk]; pc1.u[1] = xp1[1][kk];
      pc1.u[2] = xp1[2][kk]; pc1.u[3] = xp1[3][kk];
#pragma unroll
      for (int dt = 0; dt < 4; ++dt) {
        short8 vf = *(const short8*)(&Vs[buf][dt * 16 + l15][kk * 32 + lq * 8]);
        o0[dt] = __builtin_amdgcn_mfma_f32_16x16x32_bf16(vf, pc0.s8, o0[dt], 0, 0, 0);
        o1[dt] = __builtin_amdgcn_mfma_f32_16x16x32_bf16(vf, pc1.s8, o1[dt], 0, 0, 0);
      }
    }
  }

  float rl0 = 1.0f / lrun0, rl1 = 1.0f / lrun1;
  unsigned short* Or0 = O + (size_t)(b * 2048 + wrow + l15) * 512 + h * 64;
  unsigned short* Or1 = O + (size_t)(b * 2048 + wrow + 16 + l15) * 512 + h * 64;
#pragma unroll
  for (int dt = 0; dt < 4; ++dt) {
    *(unsigned int*)(Or0 + dt * 16 + lq * 4)     = pkbf(o0[dt][0] * rl0, o0[dt][1] * rl0);
    *(unsigned int*)(Or0 + dt * 16 + lq * 4 + 2) = pkbf(o0[dt][2] * rl0, o0[dt][3] * rl0);
    *(unsigned int*)(Or1 + dt * 16 + lq * 4)     = pkbf(o1[dt][0] * rl1, o1[dt][1] * rl1);
    *(unsigned int*)(Or1 + dt * 16 + lq * 4 + 2) = pkbf(o1[dt][2] * rl1, o1[dt][3] * rl1);
  }
}

extern "C" void kernel_launch(void* const* d_in, const int* in_sizes, int n_in,
                              void* d_out, int out_size, void* d_ws, size_t ws_size,
                              hipStream_t stream) {
  const float* x       = (const float*)d_in[0];
  const float* context = (const float*)d_in[1];
  const int*   mask    = (const int*)d_in[2];
  const float* Wq      = (const float*)d_in[3];
  const float* Wkv     = (const float*)d_in[4];
  const float* Wo      = (const float*)d_in[5];
  const float* bo      = (const float*)d_in[6];
  float* out = (float*)d_out;

  char* ws = (char*)d_ws;
  unsigned short* Wq_t  = (unsigned short*)(ws + 0);         //  512x512  bf16
  unsigned short* Wkv_t = (unsigned short*)(ws + 524288);    // 1024x512  bf16
  unsigned short* Wo_t  = (unsigned short*)(ws + 1572864);   //  512x512  bf16
  unsigned short* qb    = (unsigned short*)(ws + 2097152);   // 8192x512  bf16
  unsigned short* kb    = (unsigned short*)(ws + 10485760);  // 8192x512  bf16
  unsigned short* vtb   = (unsigned short*)(ws + 18874368);  // (b,h,d)x2048 bf16
  unsigned short* ab    = (unsigned short*)(ws + 27262976);  // 8192x512  bf16
  unsigned long long* mpk = (unsigned long long*)(ws + 35651584);  // 128 x u64

  const float QSCALE = 0.125f * 1.44269504088896f;  // head_dim^-0.5 * log2(e)

  prep_kernel<<<dim3(16, 8, 4), 256, 0, stream>>>(Wq, Wkv, Wo, mask,
                                                  Wq_t, Wkv_t, Wo_t, mpk);
  gemm_kernel<2, 0, true><<<dim3(4, 128), 256, 0, stream>>>(x, Wq_t, qb, nullptr, nullptr, 8192, 512, 512, QSCALE);
  gemm_kernel<4, 1, true><<<dim3(8, 64), 256, 0, stream>>>(context, Wkv_t, kb, vtb, nullptr, 8192, 1024, 512, 1.0f);
  attn_kernel<<<dim3(32, 16), 256, 0, stream>>>(qb, kb, vtb, mpk, ab);
  gemm_kernel<2, 2, false><<<dim3(4, 128), 256, 0, stream>>>(ab, Wo_t, out, nullptr, bo, 8192, 512, 512, 1.0f);
}